// Round 4
// baseline (555.003 us; speedup 1.0000x reference)
//
#include <hip/hip_runtime.h>

#define BATCH 4
#define HH 256
#define WW 256
#define HT 513   // convT output spatial
#define HO 511   // final output spatial

typedef __attribute__((ext_vector_type(8))) short bf16x8;
typedef __attribute__((ext_vector_type(4))) float f32x4;

// ---------- bf16 helpers ----------
__device__ __forceinline__ unsigned short f2bf(float f) {
    unsigned b = __float_as_uint(f);
    unsigned r = (b + 0x7fffu + ((b >> 16) & 1u)) >> 16;  // RNE
    return (unsigned short)r;
}

// async global->LDS, 16B per lane. LDS dest must be wave-uniform base (+lane*16).
typedef __attribute__((address_space(3))) unsigned int lds_u32;
typedef const __attribute__((address_space(1))) unsigned int g_u32;
__device__ __forceinline__ void gload16(const void* g, void* l) {
    __builtin_amdgcn_global_load_lds((g_u32*)g, (lds_u32*)l, 16, 0, 0);
}

// ---------- 0: zero a float4 region ----------
__global__ void k_zero(float* __restrict__ p, int n4) {
    int i = blockIdx.x * blockDim.x + threadIdx.x;
    if (i < n4) ((float4*)p)[i] = make_float4(0.f, 0.f, 0.f, 0.f);
}

// ---------- 1: scatter-add features (fp32), set occupancy ----------
__global__ void k_scatter(const float* __restrict__ feat,
                          const int* __restrict__ coors,
                          float* __restrict__ x, float* __restrict__ mask0, int N) {
    int t = blockIdx.x * blockDim.x + threadIdx.x;
    int n = t >> 5, c = t & 31;
    if (n >= N) return;
    int b  = coors[n * 3 + 0];
    int y  = coors[n * 3 + 1];
    int xx = coors[n * 3 + 2];
    float f = feat[n * 32 + c];
    int pix = (b * HH + y) * WW + xx;
    atomicAdd(&x[pix * 32 + c], f);
    if (c == 0) mask0[pix] = 1.0f;
}

// ---------- 2: 3x3 dilate mask (SAME) ----------
__global__ void k_mask1(const float* __restrict__ mask0, float* __restrict__ mask1, int total) {
    int t = blockIdx.x * blockDim.x + threadIdx.x;
    if (t >= total) return;
    int xx = t % WW;
    int y  = (t / WW) % HH;
    int b  = t / (WW * HH);
    float m = 0.f;
    #pragma unroll
    for (int dy = -1; dy <= 1; ++dy) {
        int iy = y + dy;
        if ((unsigned)iy >= HH) continue;
        #pragma unroll
        for (int dx = -1; dx <= 1; ++dx) {
            int ix = xx + dx;
            if ((unsigned)ix >= WW) continue;
            m = fmaxf(m, mask0[(b * HH + iy) * WW + ix]);
        }
    }
    mask1[t] = (m > 0.f) ? 1.f : 0.f;
}

// ---------- 2b: transpose-dilate mask: mask4[B][513][513] ----------
__global__ void k_mask4(const float* __restrict__ mask1, float* __restrict__ mask4, int total) {
    int t = blockIdx.x * blockDim.x + threadIdx.x;
    if (t >= total) return;
    int ox = t % HT;
    int oy = (t / HT) % HT;
    int b  = t / (HT * HT);
    float m = 0.f;
    #pragma unroll
    for (int ky = 0; ky < 3; ++ky) {
        int q = oy + ky - 2;
        if ((q & 1) || (unsigned)(q >> 1) >= (unsigned)HH) continue;
        int iy = q >> 1;
        #pragma unroll
        for (int kx = 0; kx < 3; ++kx) {
            int r = ox + kx - 2;
            if ((r & 1) || (unsigned)(r >> 1) >= (unsigned)WW) continue;
            m = fmaxf(m, mask1[(b * HH + iy) * WW + (r >> 1)]);
        }
    }
    mask4[t] = (m > 0.f) ? 1.f : 0.f;
}

// ---------- 2c: cast x fp32 -> bf16 (8 elems/thread) ----------
__global__ void k_cast(const float* __restrict__ src, unsigned short* __restrict__ dst, int n8) {
    int i = blockIdx.x * blockDim.x + threadIdx.x;
    if (i >= n8) return;
    float4 a = ((const float4*)src)[2 * i];
    float4 c = ((const float4*)src)[2 * i + 1];
    uint4 o;
    o.x = (unsigned)f2bf(a.x) | ((unsigned)f2bf(a.y) << 16);
    o.y = (unsigned)f2bf(a.z) | ((unsigned)f2bf(a.w) << 16);
    o.z = (unsigned)f2bf(c.x) | ((unsigned)f2bf(c.y) << 16);
    o.w = (unsigned)f2bf(c.z) | ((unsigned)f2bf(c.w) << 16);
    ((uint4*)dst)[i] = o;
}

// ---------- 2d: pack weights [K][64] fp32 -> MFMA B-fragment order ----------
__global__ void k_pack(const float* __restrict__ w, unsigned short* __restrict__ dst, int T) {
    int t = blockIdx.x * blockDim.x + threadIdx.x;
    if (t >= T * 256) return;
    int step = t >> 8;
    int r = t & 255;
    int nb = r >> 6;
    int l = r & 63;
    int k = step * 32 + ((l >> 4) * 8);
    int n = nb * 16 + (l & 15);
    unsigned short tmp[8];
    #pragma unroll
    for (int j = 0; j < 8; ++j) tmp[j] = f2bf(w[(size_t)(k + j) * 64 + n]);
    uint4 o;
    o.x = (unsigned)tmp[0] | ((unsigned)tmp[1] << 16);
    o.y = (unsigned)tmp[2] | ((unsigned)tmp[3] << 16);
    o.z = (unsigned)tmp[4] | ((unsigned)tmp[5] << 16);
    o.w = (unsigned)tmp[6] | ((unsigned)tmp[7] << 16);
    *(uint4*)(dst + (size_t)((step * 4 + nb) * 64 + l) * 8) = o;
}

// ================= pair-row CONV (512 thr, A ring-3 + B ring-2) =================
// 8 waves: waves 0-3 -> row y0, waves 4-7 -> row y0+1, each wave 64 px x 64 cout.
// A rows staged once each (4 unique rows per pair); B(ky) staged once per pair.
// Schedule: stage{A0,A1,A2,B0,B1}|bar|ky0|bar|issue{A3,B2}|ky1|bar|ky2.
// OOB rows/px stage from zero page (exact SAME-padding semantics).
template <int CIN, int IN_H, int IN_W, int OUT_H, int OUT_W, int PAD,
          bool MASKED, bool OUT_F32>
__global__ __launch_bounds__(512, 1) void k_conv2(
    const unsigned short* __restrict__ in,   // bf16 [B][IN_H][IN_W][CIN]
    const unsigned short* __restrict__ bp,   // packed B frags [T][4][64][8]
    const float* __restrict__ bias,          // [64]
    const float* __restrict__ mask,          // [B][OUT_H][OUT_W] (if MASKED)
    const unsigned short* __restrict__ zpg,  // >=16B zeros
    void* __restrict__ outv)                 // bf16 or fp32 [B][OUT_H][OUT_W][64]
{
    constexpr int H2  = CIN / 32;
    constexpr int XT  = (OUT_W + 255) / 256;
    constexpr int CPX = CIN / 8;                  // 16B chunks per pixel
    constexpr int CSH = (CIN == 64) ? 3 : 2;
    constexpr int APX = (CIN == 32) ? 272 : 264;  // staged px/row (>=258, chunks%64==0)
    constexpr int ACH = APX * CPX;                // chunks per A row
    constexpr int ASZ = APX * CIN * 2;            // bytes per A row
    constexpr int BSZ = 3 * H2 * 4096;            // bytes per B ky-tile
    constexpr int BCH = 3 * H2 * 256;             // chunks per B ky-tile
    constexpr int PAIRS = (OUT_H + 1) / 2;

    extern __shared__ __align__(16) char lds[];   // [2*BSZ B-ring][3*ASZ A-ring]

    // XCD-aware bijective swizzle
    int nwg  = (int)gridDim.x;
    int orig = (int)blockIdx.x;
    int q8 = nwg >> 3, r8 = nwg & 7;
    int xcd = orig & 7, pos = orig >> 3;
    int blk = (xcd < r8 ? xcd * (q8 + 1) : r8 * (q8 + 1) + (xcd - r8) * q8) + pos;

    int s  = blk % XT;
    int yp = (blk / XT) % PAIRS;
    int b  = blk / (XT * PAIRS);
    int y0 = yp * 2;

    int tid  = threadIdx.x;
    int lane = tid & 63;
    int wid  = tid >> 6;
    int r    = wid >> 2;          // row within pair
    int ww   = wid & 3;           // wave within row
    int m    = lane & 15;
    int quad = lane >> 4;

    int px_base = s * 256 + ww * 64;
    int pb = ww * 64 + m;
    int t0 = s * 256 - PAD;       // global input col of staged px 0

    auto stageA = [&](int rel) {
        int iy = y0 - PAD + rel;
        bool rv = (unsigned)iy < (unsigned)IN_H;
        const unsigned short* inrow = in + (size_t)(b * IN_H + iy) * IN_W * CIN;
        char* base = lds + 2 * BSZ + (rel % 3) * ASZ;
        #pragma unroll
        for (int j = 0; j < (ACH + 511) / 512; ++j) {
            int ci = j * 512 + tid;
            if (ci >= ACH) break;                 // wave-uniform (ACH%64==0)
            int p  = ci >> CSH;
            int cc = ci & (CPX - 1);
            int swz = (CIN == 64) ? (p & 7) : ((p >> 1) & 3);
            int c  = cc ^ swz;
            int t  = t0 + p;
            const unsigned short* g = (rv && (unsigned)t < (unsigned)IN_W)
                ? inrow + (size_t)t * CIN + c * 8 : zpg;
            gload16(g, base + (size_t)(ci & ~63) * 16);
        }
    };
    auto stageB = [&](int ky) {
        const uint4* bsrc = (const uint4*)bp + (size_t)ky * BCH;
        char* base = lds + (ky & 1) * BSZ;
        #pragma unroll
        for (int j = 0; j < (BCH + 511) / 512; ++j) {
            int ci = j * 512 + tid;
            if (ci >= BCH) break;                 // wave-uniform (BCH%64==0)
            gload16(bsrc + ci, base + (size_t)(ci & ~63) * 16);
        }
    };

    f32x4 acc[4][4] = {};

    auto doKy = [&](int ky) {
        const unsigned short* lA_ =
            (const unsigned short*)(lds + 2 * BSZ + ((r + ky) % 3) * ASZ);
        const unsigned short* lB_ = (const unsigned short*)(lds + (ky & 1) * BSZ);
        #pragma unroll
        for (int kx = 0; kx < 3; ++kx) {
            #pragma unroll
            for (int half = 0; half < H2; ++half) {
                int tl = kx * H2 + half;
                const unsigned short* lbt = lB_ + tl * 2048 + lane * 8;
                bf16x8 bfr[4];
                #pragma unroll
                for (int nb = 0; nb < 4; ++nb)
                    bfr[nb] = *(const bf16x8*)(lbt + nb * 512);
                #pragma unroll
                for (int f = 0; f < 4; ++f) {
                    int p = pb + f * 16 + kx;
                    int swz = (CIN == 64) ? (p & 7) : ((p >> 1) & 3);
                    int c = ((CIN == 64) ? (half * 4 + quad) : quad) ^ swz;
                    bf16x8 a = *(const bf16x8*)(lA_ + (size_t)p * CIN + c * 8);
                    #pragma unroll
                    for (int nb = 0; nb < 4; ++nb)
                        acc[f][nb] = __builtin_amdgcn_mfma_f32_16x16x32_bf16(
                            a, bfr[nb], acc[f][nb], 0, 0, 0);
                }
            }
        }
    };

    // pipeline: only the prologue stage is latency-exposed
    stageA(0); stageA(1); stageA(2); stageB(0); stageB(1);
    __syncthreads();              // vmcnt(0) drain + barrier
    doKy(0);
    __syncthreads();              // all waves done reading slot0/b0
    stageA(3); stageB(2);         // in flight during ky1 compute
    doKy(1);
    __syncthreads();              // drains A3/B2
    doKy(2);

    // epilogue
    int y = y0 + r;
    if (y < OUT_H) {
        int n0 = m;
        float bv[4];
        #pragma unroll
        for (int nb = 0; nb < 4; ++nb) bv[nb] = bias[nb * 16 + n0];
        #pragma unroll
        for (int f = 0; f < 4; ++f) {
            #pragma unroll
            for (int reg = 0; reg < 4; ++reg) {
                int i = f * 16 + quad * 4 + reg;
                int pm = px_base + i;
                if (pm >= OUT_W) continue;
                size_t pix = (size_t)(b * OUT_H + y) * OUT_W + pm;
                float mk = 1.f;
                if constexpr (MASKED) mk = mask[pix];
                #pragma unroll
                for (int nb = 0; nb < 4; ++nb) {
                    float o = fmaxf((acc[f][nb][reg] + bv[nb]) * mk, 0.f);
                    if constexpr (OUT_F32)
                        ((float*)outv)[pix * 64 + nb * 16 + n0] = o;
                    else
                        ((unsigned short*)outv)[pix * 64 + nb * 16 + n0] = f2bf(o);
                }
            }
        }
    }
}

// ================= convT (round-3 structure, unchanged) =================
enum Mode { CONV, CONVT2 };

template <int CIN, int IN_H, int IN_W, int OUT_H, int OUT_W, int PAD,
          Mode MODE, bool MASKED, bool OUT_F32>
__global__ __launch_bounds__(256, 2) void k_conv_mfma(
    const unsigned short* __restrict__ in,
    const unsigned short* __restrict__ bp,
    const float* __restrict__ bias,
    const float* __restrict__ mask,
    const unsigned short* __restrict__ zpg,
    void* __restrict__ outv)
{
    constexpr int H2  = CIN / 32;
    constexpr int XT  = (OUT_W + 255) / 256;
    constexpr int CPX = CIN / 8;
    constexpr int CSH = (CIN == 64) ? 3 : 2;
    constexpr int APX = (MODE == CONV) ? ((CIN == 32) ? 320 : 288) : 160;
    constexpr int NITER = APX * CPX / 256;
    constexpr int BBYTES = 3 * H2 * 4096;

    __shared__ __align__(16) char lds[BBYTES + APX * CIN * 2];

    int nwg  = (int)gridDim.x;
    int orig = (int)blockIdx.x;
    int q8 = nwg >> 3, r8 = nwg & 7;
    int xcd = orig & 7, pos = orig >> 3;
    int blk = (xcd < r8 ? xcd * (q8 + 1) : r8 * (q8 + 1) + (xcd - r8) * q8) + pos;

    int s = blk % XT;
    int y = (blk / XT) % OUT_H;
    int b = blk / (XT * OUT_H);
    int tid  = threadIdx.x;
    int lane = tid & 63;
    int wid  = tid >> 6;
    int m    = lane & 15;
    int quad = lane >> 4;

    int px_base, par;
    if constexpr (MODE == CONV) { px_base = s * 256 + wid * 64; par = 0; }
    else { par = wid & 1; px_base = s * 256 + (wid >> 1) * 128; }

    int nkx, kx0, kxstep;
    if constexpr (MODE == CONV) { nkx = 3; kx0 = 0; kxstep = 1; }
    else { nkx = (par == 0) ? 2 : 1; kx0 = par; kxstep = 2; }

    int t0;
    if constexpr (MODE == CONV) t0 = s * 256 - PAD;
    else                        t0 = s * 128 - 1;

    int pb;
    if constexpr (MODE == CONV) pb = wid * 64 + m;
    else                        pb = (wid >> 1) * 64 + m;

    const unsigned short* lA = (const unsigned short*)(lds + BBYTES);
    const unsigned short* lB = (const unsigned short*)lds;

    f32x4 acc[4][4] = {};

    #pragma unroll
    for (int ky = 0; ky < 3; ++ky) {
        int iy; bool rowv;
        if constexpr (MODE == CONV) {
            iy = y + ky - PAD;
            rowv = (unsigned)iy < (unsigned)IN_H;
        } else {
            int q = y + ky - 2;
            rowv = (!(q & 1)) && ((unsigned)(q >> 1) < (unsigned)IN_H);
            iy = q >> 1;
        }
        if (!rowv) continue;

        const unsigned short* inrow = in + (size_t)(b * IN_H + iy) * IN_W * CIN;

        __syncthreads();
        {
            const uint4* bsrc = (const uint4*)bp + (size_t)ky * 3 * H2 * 256;
            #pragma unroll
            for (int j = 0; j < 3 * H2; ++j)
                gload16(bsrc + j * 256 + tid,
                        lds + (size_t)(j * 256 + (tid & ~63)) * 16);
        }
        #pragma unroll
        for (int j = 0; j < NITER; ++j) {
            int ci = j * 256 + tid;
            int p  = ci >> CSH;
            int cc = ci & (CPX - 1);
            int swz = (CIN == 64) ? (p & 7) : ((p >> 1) & 3);
            int c  = cc ^ swz;
            int t  = t0 + p;
            const unsigned short* g =
                ((unsigned)t < (unsigned)IN_W) ? inrow + (size_t)t * CIN + c * 8 : zpg;
            gload16(g, lds + BBYTES + (size_t)(j * 256 + (tid & ~63)) * 16);
        }
        __syncthreads();

        #pragma unroll
        for (int i = 0; i < 3; ++i) {
            if (i < nkx) {
                int kx = kx0 + i * kxstep;
                int kxo;
                if constexpr (MODE == CONV) kxo = kx;
                else kxo = ((par + kx - 2) >> 1) + 1;
                #pragma unroll
                for (int half = 0; half < H2; ++half) {
                    int tl = kx * H2 + half;
                    const unsigned short* lbt = lB + tl * 2048 + lane * 8;
                    bf16x8 bfr[4];
                    #pragma unroll
                    for (int nb = 0; nb < 4; ++nb)
                        bfr[nb] = *(const bf16x8*)(lbt + nb * 512);
                    #pragma unroll
                    for (int f = 0; f < 4; ++f) {
                        int p = pb + f * 16 + kxo;
                        int swz = (CIN == 64) ? (p & 7) : ((p >> 1) & 3);
                        int c = ((CIN == 64) ? (half * 4 + quad) : quad) ^ swz;
                        bf16x8 a = *(const bf16x8*)(lA + (size_t)p * CIN + c * 8);
                        #pragma unroll
                        for (int nb = 0; nb < 4; ++nb)
                            acc[f][nb] = __builtin_amdgcn_mfma_f32_16x16x32_bf16(
                                a, bfr[nb], acc[f][nb], 0, 0, 0);
                    }
                }
            }
        }
    }

    int n0 = m;
    float bv[4];
    #pragma unroll
    for (int nb = 0; nb < 4; ++nb) bv[nb] = bias[nb * 16 + n0];
    #pragma unroll
    for (int f = 0; f < 4; ++f) {
        #pragma unroll
        for (int reg = 0; reg < 4; ++reg) {
            int i = f * 16 + quad * 4 + reg;
            int pm;
            if constexpr (MODE == CONV) pm = px_base + i;
            else pm = px_base + 2 * i + par;
            if (pm >= OUT_W) continue;
            size_t pix = (size_t)(b * OUT_H + y) * OUT_W + pm;
            float mk = 1.f;
            if constexpr (MASKED) mk = mask[pix];
            #pragma unroll
            for (int nb = 0; nb < 4; ++nb) {
                float o = fmaxf((acc[f][nb][reg] + bv[nb]) * mk, 0.f);
                if constexpr (OUT_F32)
                    ((float*)outv)[pix * 64 + nb * 16 + n0] = o;
                else
                    ((unsigned short*)outv)[pix * 64 + nb * 16 + n0] = f2bf(o);
            }
        }
    }
}

// ---------- host ----------
extern "C" void kernel_launch(void* const* d_in, const int* in_sizes, int n_in,
                              void* d_out, int out_size, void* d_ws, size_t ws_size,
                              hipStream_t stream) {
    const float* feat = (const float*)d_in[0];
    const int* coors  = (const int*)d_in[1];
    const float* w1 = (const float*)d_in[3];
    const float* b1 = (const float*)d_in[4];
    const float* w2 = (const float*)d_in[5];
    const float* b2 = (const float*)d_in[6];
    const float* w3 = (const float*)d_in[7];
    const float* b3 = (const float*)d_in[8];
    const float* wt = (const float*)d_in[9];
    const float* bt = (const float*)d_in[10];
    const float* w5 = (const float*)d_in[11];
    const float* b5 = (const float*)d_in[12];

    int N = in_sizes[0] / 32;  // 200000

    const size_t MB = 1024 * 1024;
    char* ws = (char*)d_ws;
    unsigned short* pk1 = (unsigned short*)(ws);
    unsigned short* pk2 = (unsigned short*)(ws + 36864);
    unsigned short* pk3 = (unsigned short*)(ws + 110592);
    unsigned short* pkt = (unsigned short*)(ws + 184320);
    unsigned short* pk5 = (unsigned short*)(ws + 258048);
    unsigned short* zpg = (unsigned short*)(ws + 960 * 1024);
    float* mask1 = (float*)(ws + 1 * MB);
    float* mask4 = (float*)(ws + 2 * MB);
    float* mask0 = (float*)(ws + 7 * MB);
    float* x_f32 = (float*)(ws + 8 * MB);
    unsigned short* x_bf  = (unsigned short*)(ws + 42 * MB);
    unsigned short* h1    = (unsigned short*)(ws + 59 * MB);
    unsigned short* h2    = (unsigned short*)(ws + 93 * MB);
    unsigned short* h3    = (unsigned short*)(ws + 8 * MB);
    unsigned short* h4    = (unsigned short*)(ws + 42 * MB);

    int nz4 = (262144 + 8388608) / 4;
    k_zero<<<(nz4 + 255) / 256, 256, 0, stream>>>(mask0, nz4);
    k_zero<<<1, 16, 0, stream>>>((float*)zpg, 16);

    k_scatter<<<(N * 32 + 255) / 256, 256, 0, stream>>>(feat, coors, x_f32, mask0, N);

    k_mask1<<<(BATCH * HH * WW) / 256, 256, 0, stream>>>(mask0, mask1, BATCH * HH * WW);
    int m4tot = BATCH * HT * HT;
    k_mask4<<<(m4tot + 255) / 256, 256, 0, stream>>>(mask1, mask4, m4tot);
    k_cast<<<(1048576 + 255) / 256, 256, 0, stream>>>(x_f32, x_bf, 1048576);
    k_pack<<<9, 256, 0, stream>>>(w1, pk1, 9);
    k_pack<<<18, 256, 0, stream>>>(w2, pk2, 18);
    k_pack<<<18, 256, 0, stream>>>(w3, pk3, 18);
    k_pack<<<18, 256, 0, stream>>>(wt, pkt, 18);
    k_pack<<<18, 256, 0, stream>>>(w5, pk5, 18);

    // pair-row CONV stack. dynamic LDS: [2*BSZ][3*ASZ]
    constexpr size_t LDS32 = 2 * 12288 + 3 * (272 * 32 * 2);   // 76,800 B
    constexpr size_t LDS64 = 2 * 24576 + 3 * (264 * 64 * 2);   // 150,528 B

    k_conv2<32, 256, 256, 256, 256, 1, true, false>
        <<<BATCH * 128 * 1, 512, LDS32, stream>>>(x_bf, pk1, b1, mask1, zpg, h1);
    k_conv2<64, 256, 256, 256, 256, 1, true, false>
        <<<BATCH * 128 * 1, 512, LDS64, stream>>>(h1, pk2, b2, mask1, zpg, h2);
    k_conv2<64, 256, 256, 256, 256, 1, true, false>
        <<<BATCH * 128 * 1, 512, LDS64, stream>>>(h2, pk3, b3, mask1, zpg, h3);

    // transpose conv 256 -> 513 (round-3 structure)
    k_conv_mfma<64, 256, 256, HT, HT, 0, CONVT2, true, false>
        <<<BATCH * HT * 3, 256, 0, stream>>>(h3, pkt, bt, mask4, zpg, h4);

    // final VALID conv 513 -> 511 into d_out (fp32), pair-row
    k_conv2<64, HT, HT, HO, HO, 0, false, true>
        <<<BATCH * 256 * 2, 512, LDS64, stream>>>(h4, pk5, b5, nullptr, zpg, (float*)d_out);
}